// Round 1
// baseline (964.270 us; speedup 1.0000x reference)
//
#include <hip/hip_runtime.h>
#include <cstddef>

#define CLS 128  // NUM_CLASSES

// ---------------------------------------------------------------------------
// Kernel 1: gather each row's own type-slot slice into compact [n][128] buffer
// ---------------------------------------------------------------------------
__global__ void gather_slots(const float* __restrict__ ft, const int* __restrict__ types,
                             float* __restrict__ S, int n, int d) {
  int g = blockIdx.x * blockDim.x + threadIdx.x;
  int total = n * (CLS / 4);
  if (g >= total) return;
  int row = g >> 5;   // CLS/4 == 32 float4 per row
  int c4 = g & 31;
  int t = types[row];
  const float4* src = reinterpret_cast<const float4*>(ft + (size_t)row * d + (size_t)t * CLS);
  float4* dst = reinterpret_cast<float4*>(S + (size_t)row * CLS);
  dst[c4] = src[c4];
}

// ---------------------------------------------------------------------------
// Kernel 2: bucket row indices by type (counting sort, order within type
// arbitrary). block 0 -> side 1, block 1 -> side 2.
// hdr layout (ints): [0..8]=off1, [9..17]=off2, [18..26]=tileOff, [27]=totalTiles,
//                    [28..35]=ntc per type
// ---------------------------------------------------------------------------
__global__ void build_groups(const int* __restrict__ t1, const int* __restrict__ t2,
                             int n1, int n2, int T,
                             int* __restrict__ idx1, int* __restrict__ idx2,
                             int* __restrict__ hdr) {
  __shared__ int cnt[32];
  __shared__ int cur[32];
  const int* tp = (blockIdx.x == 0) ? t1 : t2;
  int n = (blockIdx.x == 0) ? n1 : n2;
  int* idx = (blockIdx.x == 0) ? idx1 : idx2;
  int* off = hdr + ((blockIdx.x == 0) ? 0 : 9);

  if ((int)threadIdx.x < 32) cnt[threadIdx.x] = 0;
  __syncthreads();
  for (int i = threadIdx.x; i < n; i += blockDim.x) {
    int t = tp[i] & 31;
    atomicAdd(&cnt[t], 1);
  }
  __syncthreads();
  if (threadIdx.x == 0) {
    int s = 0;
    for (int p = 0; p < T; ++p) { off[p] = s; cur[p] = s; s += cnt[p]; }
    off[T] = s;
  }
  __syncthreads();
  for (int i = threadIdx.x; i < n; i += blockDim.x) {
    int t = tp[i] & 31;
    int pos = atomicAdd(&cur[t], 1);
    idx[pos] = i;
  }
}

// ---------------------------------------------------------------------------
// Kernel 3: per-type tile bookkeeping for the grouped full GEMM (128x128 tiles)
// ---------------------------------------------------------------------------
__global__ void build_tiles(int T, int* __restrict__ hdr) {
  if (threadIdx.x == 0 && blockIdx.x == 0) {
    const int* off1 = hdr;
    const int* off2 = hdr + 9;
    int* toff = hdr + 18;
    int* ntcA = hdr + 28;
    int s = 0;
    for (int p = 0; p < T; ++p) {
      int c1 = off1[p + 1] - off1[p];
      int c2 = off2[p + 1] - off2[p];
      int ntr = (c1 + 127) / 128;
      int ntc = (c2 + 127) / 128;
      ntcA[p] = ntc;
      toff[p] = s;
      s += ntr * ntc;
    }
    toff[T] = s;
    hdr[27] = s;
  }
}

// ---------------------------------------------------------------------------
// Kernel 4: cross GEMM  out[i][j] = sum_{k<128} S1[i][k]*S2[j][k]
// 128x128 tile, 256 threads, 8x8 microtile, BK=16
// ---------------------------------------------------------------------------
__global__ __launch_bounds__(256) void cross_gemm(
    const float* __restrict__ S1, const float* __restrict__ S2,
    float* __restrict__ out, int n2) {
  __shared__ float As[16][128];
  __shared__ float Bs[16][128];
  const int tid = threadIdx.x;
  const int tx = tid & 15, ty = tid >> 4;
  const int bm = blockIdx.y * 128, bn = blockIdx.x * 128;
  const int lr = tid >> 2, lk = (tid & 3) << 2;

  float acc[8][8];
#pragma unroll
  for (int i = 0; i < 8; ++i)
#pragma unroll
    for (int j = 0; j < 8; ++j) acc[i][j] = 0.f;

  const float* a0p = S1 + (size_t)(bm + lr) * CLS + lk;
  const float* a1p = a0p + (size_t)64 * CLS;
  const float* b0p = S2 + (size_t)(bn + lr) * CLS + lk;
  const float* b1p = b0p + (size_t)64 * CLS;

  for (int k0 = 0; k0 < CLS; k0 += 16) {
    float4 a0 = *reinterpret_cast<const float4*>(a0p + k0);
    float4 a1 = *reinterpret_cast<const float4*>(a1p + k0);
    float4 b0 = *reinterpret_cast<const float4*>(b0p + k0);
    float4 b1 = *reinterpret_cast<const float4*>(b1p + k0);
    __syncthreads();
    As[lk + 0][lr] = a0.x; As[lk + 1][lr] = a0.y; As[lk + 2][lr] = a0.z; As[lk + 3][lr] = a0.w;
    As[lk + 0][lr + 64] = a1.x; As[lk + 1][lr + 64] = a1.y; As[lk + 2][lr + 64] = a1.z; As[lk + 3][lr + 64] = a1.w;
    Bs[lk + 0][lr] = b0.x; Bs[lk + 1][lr] = b0.y; Bs[lk + 2][lr] = b0.z; Bs[lk + 3][lr] = b0.w;
    Bs[lk + 0][lr + 64] = b1.x; Bs[lk + 1][lr + 64] = b1.y; Bs[lk + 2][lr + 64] = b1.z; Bs[lk + 3][lr + 64] = b1.w;
    __syncthreads();
#pragma unroll
    for (int k = 0; k < 16; ++k) {
      float4 av0 = *reinterpret_cast<const float4*>(&As[k][ty * 8]);
      float4 av1 = *reinterpret_cast<const float4*>(&As[k][ty * 8 + 4]);
      float4 bv0 = *reinterpret_cast<const float4*>(&Bs[k][tx * 8]);
      float4 bv1 = *reinterpret_cast<const float4*>(&Bs[k][tx * 8 + 4]);
      float a[8] = {av0.x, av0.y, av0.z, av0.w, av1.x, av1.y, av1.z, av1.w};
      float b[8] = {bv0.x, bv0.y, bv0.z, bv0.w, bv1.x, bv1.y, bv1.z, bv1.w};
#pragma unroll
      for (int i = 0; i < 8; ++i)
#pragma unroll
        for (int j = 0; j < 8; ++j) acc[i][j] = fmaf(a[i], b[j], acc[i][j]);
    }
  }

  const size_t orow0 = (size_t)bm + (size_t)ty * 8;
  const int ocol = bn + tx * 8;
#pragma unroll
  for (int i = 0; i < 8; ++i) {
    float* dst = out + (orow0 + i) * (size_t)n2 + ocol;
    *reinterpret_cast<float4*>(dst) = make_float4(acc[i][0], acc[i][1], acc[i][2], acc[i][3]);
    *reinterpret_cast<float4*>(dst + 4) = make_float4(acc[i][4], acc[i][5], acc[i][6], acc[i][7]);
  }
}

// ---------------------------------------------------------------------------
// Kernel 5: grouped full GEMM (K=d) over same-type pairs; overwrites out.
// Persistent blocks loop over (type, tileR, tileC) work items.
// ---------------------------------------------------------------------------
__global__ __launch_bounds__(256) void grouped_full(
    const float* __restrict__ ft1, const float* __restrict__ ft2,
    const int* __restrict__ idx1, const int* __restrict__ idx2,
    const int* __restrict__ hdr, float* __restrict__ out,
    int d, int n2) {
  __shared__ float As[16][128];
  __shared__ float Bs[16][128];
  const int* off1 = hdr;
  const int* off2 = hdr + 9;
  const int* toff = hdr + 18;
  const int* ntcA = hdr + 28;
  const int total = hdr[27];

  const int tid = threadIdx.x;
  const int tx = tid & 15, ty = tid >> 4;
  const int lr = tid >> 2, lk = (tid & 3) << 2;
  const float4 zero4 = make_float4(0.f, 0.f, 0.f, 0.f);

  for (int wi = blockIdx.x; wi < total; wi += gridDim.x) {
    int p = 0;
    while (wi >= toff[p + 1]) ++p;
    const int local = wi - toff[p];
    const int ntc = ntcA[p];
    const int tr = local / ntc, tc = local % ntc;
    const int base1 = off1[p], base2 = off2[p];
    const int c1 = off1[p + 1] - base1, c2 = off2[p + 1] - base2;
    const int r0 = tr * 128, c0 = tc * 128;

    const int ar0 = r0 + lr, ar1 = r0 + lr + 64;
    const int br0 = c0 + lr, br1 = c0 + lr + 64;
    const bool va0 = ar0 < c1, va1 = ar1 < c1, vb0 = br0 < c2, vb1 = br1 < c2;
    const float* a0p = ft1 + (size_t)(va0 ? idx1[base1 + ar0] : 0) * d + lk;
    const float* a1p = ft1 + (size_t)(va1 ? idx1[base1 + ar1] : 0) * d + lk;
    const float* b0p = ft2 + (size_t)(vb0 ? idx2[base2 + br0] : 0) * d + lk;
    const float* b1p = ft2 + (size_t)(vb1 ? idx2[base2 + br1] : 0) * d + lk;

    float acc[8][8];
#pragma unroll
    for (int i = 0; i < 8; ++i)
#pragma unroll
      for (int j = 0; j < 8; ++j) acc[i][j] = 0.f;

    for (int k0 = 0; k0 < d; k0 += 16) {
      float4 a0 = va0 ? *reinterpret_cast<const float4*>(a0p + k0) : zero4;
      float4 a1 = va1 ? *reinterpret_cast<const float4*>(a1p + k0) : zero4;
      float4 b0 = vb0 ? *reinterpret_cast<const float4*>(b0p + k0) : zero4;
      float4 b1 = vb1 ? *reinterpret_cast<const float4*>(b1p + k0) : zero4;
      __syncthreads();
      As[lk + 0][lr] = a0.x; As[lk + 1][lr] = a0.y; As[lk + 2][lr] = a0.z; As[lk + 3][lr] = a0.w;
      As[lk + 0][lr + 64] = a1.x; As[lk + 1][lr + 64] = a1.y; As[lk + 2][lr + 64] = a1.z; As[lk + 3][lr + 64] = a1.w;
      Bs[lk + 0][lr] = b0.x; Bs[lk + 1][lr] = b0.y; Bs[lk + 2][lr] = b0.z; Bs[lk + 3][lr] = b0.w;
      Bs[lk + 0][lr + 64] = b1.x; Bs[lk + 1][lr + 64] = b1.y; Bs[lk + 2][lr + 64] = b1.z; Bs[lk + 3][lr + 64] = b1.w;
      __syncthreads();
#pragma unroll
      for (int k = 0; k < 16; ++k) {
        float4 av0 = *reinterpret_cast<const float4*>(&As[k][ty * 8]);
        float4 av1 = *reinterpret_cast<const float4*>(&As[k][ty * 8 + 4]);
        float4 bv0 = *reinterpret_cast<const float4*>(&Bs[k][tx * 8]);
        float4 bv1 = *reinterpret_cast<const float4*>(&Bs[k][tx * 8 + 4]);
        float a[8] = {av0.x, av0.y, av0.z, av0.w, av1.x, av1.y, av1.z, av1.w};
        float b[8] = {bv0.x, bv0.y, bv0.z, bv0.w, bv1.x, bv1.y, bv1.z, bv1.w};
#pragma unroll
        for (int i = 0; i < 8; ++i)
#pragma unroll
          for (int j = 0; j < 8; ++j) acc[i][j] = fmaf(a[i], b[j], acc[i][j]);
      }
    }

    // scattered epilogue: overwrite same-type pairs with the full dot product
    const int rloc = r0 + ty * 8;
    const int cloc = c0 + tx * 8;
    int grows[8], gcols[8];
#pragma unroll
    for (int i = 0; i < 8; ++i) grows[i] = (rloc + i < c1) ? idx1[base1 + rloc + i] : -1;
#pragma unroll
    for (int j = 0; j < 8; ++j) gcols[j] = (cloc + j < c2) ? idx2[base2 + cloc + j] : -1;
#pragma unroll
    for (int i = 0; i < 8; ++i) {
      if (grows[i] < 0) continue;
      float* orow = out + (size_t)grows[i] * n2;
#pragma unroll
      for (int j = 0; j < 8; ++j) {
        if (gcols[j] >= 0) orow[gcols[j]] = acc[i][j];
      }
    }
  }
}

// ---------------------------------------------------------------------------
extern "C" void kernel_launch(void* const* d_in, const int* in_sizes, int n_in,
                              void* d_out, int out_size, void* d_ws, size_t ws_size,
                              hipStream_t stream) {
  const float* ft1 = (const float*)d_in[0];
  const float* ft2 = (const float*)d_in[1];
  const int* t1 = (const int*)d_in[2];
  const int* t2 = (const int*)d_in[3];
  float* out = (float*)d_out;

  const int n1 = in_sizes[2];
  const int n2 = in_sizes[3];
  const int d = in_sizes[0] / n1;   // 1024
  const int T = d / CLS;            // 8

  // workspace carve-up: S1 (n1*128 f32) | S2 (n2*128 f32) | idx1 | idx2 | hdr(64 ints)
  float* S1 = (float*)d_ws;
  float* S2 = S1 + (size_t)n1 * CLS;
  int* idx1 = (int*)(S2 + (size_t)n2 * CLS);
  int* idx2 = idx1 + n1;
  int* hdr = idx2 + n2;

  {
    int blocks = (n1 * (CLS / 4) + 255) / 256;
    gather_slots<<<blocks, 256, 0, stream>>>(ft1, t1, S1, n1, d);
  }
  {
    int blocks = (n2 * (CLS / 4) + 255) / 256;
    gather_slots<<<blocks, 256, 0, stream>>>(ft2, t2, S2, n2, d);
  }
  build_groups<<<2, 256, 0, stream>>>(t1, t2, n1, n2, T, idx1, idx2, hdr);
  build_tiles<<<1, 64, 0, stream>>>(T, hdr);

  dim3 grid(n2 / 128, n1 / 128);
  cross_gemm<<<grid, 256, 0, stream>>>(S1, S2, out, n2);
  grouped_full<<<1024, 256, 0, stream>>>(ft1, ft2, idx1, idx2, hdr, out, d, n2);
}

// Round 2
// 781.875 us; speedup vs baseline: 1.2333x; 1.2333x over previous
//
#include <hip/hip_runtime.h>
#include <cstddef>

#define CLS 128  // NUM_CLASSES

typedef _Float16 half8 __attribute__((ext_vector_type(8)));
typedef float f32x4 __attribute__((ext_vector_type(4)));

__device__ inline half8 cvt8(float4 a, float4 b) {
  half8 r;
  r[0] = (_Float16)a.x; r[1] = (_Float16)a.y; r[2] = (_Float16)a.z; r[3] = (_Float16)a.w;
  r[4] = (_Float16)b.x; r[5] = (_Float16)b.y; r[6] = (_Float16)b.z; r[7] = (_Float16)b.w;
  return r;
}

// ---------------------------------------------------------------------------
// Kernel 1: gather each row's slot slice, convert to f16: S[row][0..128)
// one thread per 8 elements
// ---------------------------------------------------------------------------
__global__ void gather_f16(const float* __restrict__ ft, const int* __restrict__ types,
                           _Float16* __restrict__ S, int n, int d) {
  int g = blockIdx.x * blockDim.x + threadIdx.x;
  if (g >= n * (CLS / 8)) return;
  int row = g >> 4;          // 16 chunks of 8 per row
  int c = (g & 15) * 8;
  int t = types[row] & 31;
  const float4* src = reinterpret_cast<const float4*>(ft + (size_t)row * d + (size_t)t * CLS + c);
  *reinterpret_cast<half8*>(S + (size_t)row * CLS + c) = cvt8(src[0], src[1]);
}

// ---------------------------------------------------------------------------
// Kernel 2: bucket row indices by type. block 0 -> side 1, block 1 -> side 2.
// hdr ints: [0..8]=off1 [9..17]=off2 [18..26]=tileOff [27]=totalTiles [28..35]=ntc
// ---------------------------------------------------------------------------
__global__ void build_groups(const int* __restrict__ t1, const int* __restrict__ t2,
                             int n1, int n2, int T,
                             int* __restrict__ idx1, int* __restrict__ idx2,
                             int* __restrict__ hdr) {
  __shared__ int cnt[32];
  __shared__ int cur[32];
  const int* tp = (blockIdx.x == 0) ? t1 : t2;
  int n = (blockIdx.x == 0) ? n1 : n2;
  int* idx = (blockIdx.x == 0) ? idx1 : idx2;
  int* off = hdr + ((blockIdx.x == 0) ? 0 : 9);

  if ((int)threadIdx.x < 32) cnt[threadIdx.x] = 0;
  __syncthreads();
  for (int i = threadIdx.x; i < n; i += blockDim.x) atomicAdd(&cnt[tp[i] & 31], 1);
  __syncthreads();
  if (threadIdx.x == 0) {
    int s = 0;
    for (int p = 0; p < T; ++p) { off[p] = s; cur[p] = s; s += cnt[p]; }
    off[T] = s;
  }
  __syncthreads();
  for (int i = threadIdx.x; i < n; i += blockDim.x) {
    int pos = atomicAdd(&cur[tp[i] & 31], 1);
    idx[pos] = i;
  }
}

__global__ void build_tiles(int T, int* __restrict__ hdr) {
  if (threadIdx.x == 0 && blockIdx.x == 0) {
    const int* off1 = hdr;
    const int* off2 = hdr + 9;
    int* toff = hdr + 18;
    int* ntcA = hdr + 28;
    int s = 0;
    for (int p = 0; p < T; ++p) {
      int c1 = off1[p + 1] - off1[p];
      int c2 = off2[p + 1] - off2[p];
      int ntr = (c1 + 127) / 128;
      int ntc = (c2 + 127) / 128;
      ntcA[p] = ntc;
      toff[p] = s;
      s += ntr * ntc;
    }
    toff[T] = s;
    hdr[27] = s;
  }
}

// ---------------------------------------------------------------------------
// Kernel 3: cross GEMM out[i][j] = S1h[i][:] . S2h[j][:]  (K=128), f16 MFMA.
// 128x128 block tile, 4 waves (2x2), wave tile 64x64 (4x4 frags of 16x16).
// No LDS: S1h/S2h total 4 MB -> L2 resident; frags read direct.
// ---------------------------------------------------------------------------
__global__ __launch_bounds__(256) void cross_f16(
    const _Float16* __restrict__ S1h, const _Float16* __restrict__ S2h,
    float* __restrict__ out, int n2) {
  const int lane = threadIdx.x & 63;
  const int w = threadIdx.x >> 6;
  const int wr = w >> 1, wc = w & 1;
  const int bm = blockIdx.y * 128, bn = blockIdx.x * 128;
  const int lr = lane & 15;
  const int ko = (lane >> 4) * 8;  // k offset within a 32-chunk

  f32x4 acc[4][4] = {};

  const _Float16* a_base = S1h + (size_t)(bm + wr * 64 + lr) * CLS + ko;
  const _Float16* b_base = S2h + (size_t)(bn + wc * 64 + lr) * CLS + ko;

#pragma unroll
  for (int kc = 0; kc < CLS / 32; ++kc) {
    half8 af[4], bf[4];
#pragma unroll
    for (int i = 0; i < 4; ++i) {
      af[i] = *reinterpret_cast<const half8*>(a_base + (size_t)i * 16 * CLS + kc * 32);
      bf[i] = *reinterpret_cast<const half8*>(b_base + (size_t)i * 16 * CLS + kc * 32);
    }
#pragma unroll
    for (int i = 0; i < 4; ++i)
#pragma unroll
      for (int j = 0; j < 4; ++j)
        acc[i][j] = __builtin_amdgcn_mfma_f32_16x16x32_f16(af[i], bf[j], acc[i][j], 0, 0, 0);
  }

  // C/D layout: col = lane&15, row = (lane>>4)*4 + q   [m89-verified]
  const int orow = bm + wr * 64 + (lane >> 4) * 4;
  const int ocol = bn + wc * 64 + (lane & 15);
#pragma unroll
  for (int i = 0; i < 4; ++i)
#pragma unroll
    for (int q = 0; q < 4; ++q) {
      float* dst = out + (size_t)(orow + i * 16 + q) * n2 + ocol;
#pragma unroll
      for (int j = 0; j < 4; ++j) dst[j * 16] = acc[i][j][q];
    }
}

// ---------------------------------------------------------------------------
// Kernel 4: grouped full GEMM (K=d) over same-type tiles, f16 MFMA.
// BK=32, reg-staged gather + on-the-fly f32->f16, XOR-swizzled LDS
// (byte ^= (row&3)<<4 keeps ds_read_b128 at the 8-way wave64 floor).
// ---------------------------------------------------------------------------
__global__ __launch_bounds__(256) void grouped_f16(
    const float* __restrict__ ft1, const float* __restrict__ ft2,
    const int* __restrict__ idx1, const int* __restrict__ idx2,
    const int* __restrict__ hdr, float* __restrict__ out,
    int d, int n2) {
  __shared__ _Float16 As[128 * 32];
  __shared__ _Float16 Bs[128 * 32];
  const int* off1 = hdr;
  const int* off2 = hdr + 9;
  const int* toff = hdr + 18;
  const int* ntcA = hdr + 28;
  const int total = hdr[27];

  const int tid = threadIdx.x;
  const int lane = tid & 63;
  const int w = tid >> 6;
  const int wr = w >> 1, wc = w & 1;
  const int srow = tid >> 1;   // staging row 0..127
  const int shalf = tid & 1;   // which 16-float half of the 32-k chunk
  const float4 zero4 = make_float4(0.f, 0.f, 0.f, 0.f);

  for (int wi = blockIdx.x; wi < total; wi += gridDim.x) {
    int p = 0;
    while (wi >= toff[p + 1]) ++p;
    const int local = wi - toff[p];
    const int ntc = ntcA[p];
    const int tr = local / ntc, tc = local % ntc;
    const int base1 = off1[p], base2 = off2[p];
    const int c1 = off1[p + 1] - base1, c2 = off2[p + 1] - base2;
    const int r0 = tr * 128, c0 = tc * 128;

    const bool va = (r0 + srow) < c1;
    const bool vb = (c0 + srow) < c2;
    const float* ap = ft1 + (size_t)(va ? idx1[base1 + r0 + srow] : 0) * d + shalf * 16;
    const float* bp = ft2 + (size_t)(vb ? idx2[base2 + c0 + srow] : 0) * d + shalf * 16;

    f32x4 acc[4][4] = {};

    float4 ra[4], rb[4];
#pragma unroll
    for (int q = 0; q < 4; ++q) {
      ra[q] = va ? *reinterpret_cast<const float4*>(ap + q * 4) : zero4;
      rb[q] = vb ? *reinterpret_cast<const float4*>(bp + q * 4) : zero4;
    }

    const int wbyte = srow * 64 + shalf * 32;
    const int wswz = (srow & 3) << 4;

    for (int k0 = 0; k0 < d; k0 += 32) {
      __syncthreads();  // previous iteration's frag reads done
      {
        half8 ha0 = cvt8(ra[0], ra[1]), ha1 = cvt8(ra[2], ra[3]);
        half8 hb0 = cvt8(rb[0], rb[1]), hb1 = cvt8(rb[2], rb[3]);
        *reinterpret_cast<half8*>((char*)As + ((wbyte + 0) ^ wswz)) = ha0;
        *reinterpret_cast<half8*>((char*)As + ((wbyte + 16) ^ wswz)) = ha1;
        *reinterpret_cast<half8*>((char*)Bs + ((wbyte + 0) ^ wswz)) = hb0;
        *reinterpret_cast<half8*>((char*)Bs + ((wbyte + 16) ^ wswz)) = hb1;
      }
      __syncthreads();
      if (k0 + 32 < d) {  // issue next chunk's global loads before the MFMAs
#pragma unroll
        for (int q = 0; q < 4; ++q) {
          ra[q] = va ? *reinterpret_cast<const float4*>(ap + k0 + 32 + q * 4) : zero4;
          rb[q] = vb ? *reinterpret_cast<const float4*>(bp + k0 + 32 + q * 4) : zero4;
        }
      }
      half8 af[4], bf[4];
#pragma unroll
      for (int i = 0; i < 4; ++i) {
        const int arow = wr * 64 + i * 16 + (lane & 15);
        const int aoff = (arow * 64 + (lane >> 4) * 16) ^ ((arow & 3) << 4);
        af[i] = *reinterpret_cast<const half8*>((const char*)As + aoff);
        const int brow = wc * 64 + i * 16 + (lane & 15);
        const int boff = (brow * 64 + (lane >> 4) * 16) ^ ((brow & 3) << 4);
        bf[i] = *reinterpret_cast<const half8*>((const char*)Bs + boff);
      }
#pragma unroll
      for (int i = 0; i < 4; ++i)
#pragma unroll
        for (int j = 0; j < 4; ++j)
          acc[i][j] = __builtin_amdgcn_mfma_f32_16x16x32_f16(af[i], bf[j], acc[i][j], 0, 0, 0);
    }

    // scatter epilogue: overwrite same-type pairs with full-K dot
    int gcols[4];
#pragma unroll
    for (int j = 0; j < 4; ++j) {
      const int cl = wc * 64 + j * 16 + (lane & 15);
      gcols[j] = (c0 + cl < c2) ? idx2[base2 + c0 + cl] : -1;
    }
#pragma unroll
    for (int i = 0; i < 4; ++i) {
#pragma unroll
      for (int q = 0; q < 4; ++q) {
        const int rl = wr * 64 + i * 16 + (lane >> 4) * 4 + q;
        if (r0 + rl >= c1) continue;
        const int grow = idx1[base1 + r0 + rl];
        float* orow = out + (size_t)grow * n2;
#pragma unroll
        for (int j = 0; j < 4; ++j)
          if (gcols[j] >= 0) orow[gcols[j]] = acc[i][j][q];
      }
    }
    __syncthreads();  // keep LDS stable until all waves finish reading
  }
}

// ---------------------------------------------------------------------------
extern "C" void kernel_launch(void* const* d_in, const int* in_sizes, int n_in,
                              void* d_out, int out_size, void* d_ws, size_t ws_size,
                              hipStream_t stream) {
  const float* ft1 = (const float*)d_in[0];
  const float* ft2 = (const float*)d_in[1];
  const int* t1 = (const int*)d_in[2];
  const int* t2 = (const int*)d_in[3];
  float* out = (float*)d_out;

  const int n1 = in_sizes[2];
  const int n2 = in_sizes[3];
  const int d = in_sizes[0] / n1;  // 1024
  const int T = d / CLS;           // 8

  // ws carve-up: S1h (n1*128 f16) | S2h (n2*128 f16) | idx1 | idx2 | hdr
  _Float16* S1h = (_Float16*)d_ws;
  _Float16* S2h = S1h + (size_t)n1 * CLS;
  int* idx1 = (int*)(S2h + (size_t)n2 * CLS);
  int* idx2 = idx1 + n1;
  int* hdr = idx2 + n2;

  gather_f16<<<(n1 * (CLS / 8) + 255) / 256, 256, 0, stream>>>(ft1, t1, S1h, n1, d);
  gather_f16<<<(n2 * (CLS / 8) + 255) / 256, 256, 0, stream>>>(ft2, t2, S2h, n2, d);
  build_groups<<<2, 256, 0, stream>>>(t1, t2, n1, n2, T, idx1, idx2, hdr);
  build_tiles<<<1, 64, 0, stream>>>(T, hdr);

  dim3 grid(n2 / 128, n1 / 128);
  cross_f16<<<grid, 256, 0, stream>>>(S1h, S2h, out, n2);
  grouped_f16<<<1024, 256, 0, stream>>>(ft1, ft2, idx1, idx2, hdr, out, d, n2);
}

// Round 3
// 538.638 us; speedup vs baseline: 1.7902x; 1.4516x over previous
//
#include <hip/hip_runtime.h>
#include <cstddef>
#include <cstdint>

#define CLS 128  // NUM_CLASSES

typedef _Float16 half8 __attribute__((ext_vector_type(8)));
typedef float f32x4 __attribute__((ext_vector_type(4)));

#define GLOAD(g, l)                                                        \
  __builtin_amdgcn_global_load_lds(                                        \
      (const __attribute__((address_space(1))) unsigned int*)(g),          \
      (__attribute__((address_space(3))) unsigned int*)(l), 16, 0, 0)

__device__ inline half8 cvt8(float4 a, float4 b) {
  half8 r;
  r[0] = (_Float16)a.x; r[1] = (_Float16)a.y; r[2] = (_Float16)a.z; r[3] = (_Float16)a.w;
  r[4] = (_Float16)b.x; r[5] = (_Float16)b.y; r[6] = (_Float16)b.z; r[7] = (_Float16)b.w;
  return r;
}

// ---------------------------------------------------------------------------
// gather_f16: slot slices in ORIGINAL row order (cross-GEMM operands)
// ---------------------------------------------------------------------------
__global__ void gather_f16(const float* __restrict__ ft, const int* __restrict__ types,
                           _Float16* __restrict__ S, int n, int d) {
  int g = blockIdx.x * blockDim.x + threadIdx.x;
  if (g >= n * (CLS / 8)) return;
  int row = g >> 4;
  int c = (g & 15) * 8;
  int t = types[row] & 31;
  const float4* src = reinterpret_cast<const float4*>(ft + (size_t)row * d + (size_t)t * CLS + c);
  *reinterpret_cast<half8*>(S + (size_t)row * CLS + c) = cvt8(src[0], src[1]);
}

// ---------------------------------------------------------------------------
// gather_sorted: full rows, type-sorted order, f16 (grouped-GEMM operands)
// ---------------------------------------------------------------------------
__global__ void gather_sorted(const float* __restrict__ ft, const int* __restrict__ idx,
                              _Float16* __restrict__ G, int n, int d) {
  int g = blockIdx.x * blockDim.x + threadIdx.x;
  int per = d >> 3;
  if (g >= n * per) return;
  int pos = g / per;
  int c = (g % per) * 8;
  int src_row = idx[pos];
  const float4* s = reinterpret_cast<const float4*>(ft + (size_t)src_row * d + c);
  *reinterpret_cast<half8*>(G + (size_t)pos * d + c) = cvt8(s[0], s[1]);
}

// ---------------------------------------------------------------------------
// build_groups: bucket rows by type.
// hdr ints: [0..8]=off1 [9..17]=off2 [18..26]=tileOff [27]=totalTiles
//           [28..35]=ntc [36..43]=ntr
// ---------------------------------------------------------------------------
__global__ void build_groups(const int* __restrict__ t1, const int* __restrict__ t2,
                             int n1, int n2, int T,
                             int* __restrict__ idx1, int* __restrict__ idx2,
                             int* __restrict__ hdr) {
  __shared__ int cnt[32];
  __shared__ int cur[32];
  const int* tp = (blockIdx.x == 0) ? t1 : t2;
  int n = (blockIdx.x == 0) ? n1 : n2;
  int* idx = (blockIdx.x == 0) ? idx1 : idx2;
  int* off = hdr + ((blockIdx.x == 0) ? 0 : 9);

  if ((int)threadIdx.x < 32) cnt[threadIdx.x] = 0;
  __syncthreads();
  for (int i = threadIdx.x; i < n; i += blockDim.x) atomicAdd(&cnt[tp[i] & 31], 1);
  __syncthreads();
  if (threadIdx.x == 0) {
    int s = 0;
    for (int p = 0; p < T; ++p) { off[p] = s; cur[p] = s; s += cnt[p]; }
    off[T] = s;
  }
  __syncthreads();
  for (int i = threadIdx.x; i < n; i += blockDim.x) {
    int pos = atomicAdd(&cur[tp[i] & 31], 1);
    idx[pos] = i;
  }
}

__global__ void build_tiles(int T, int* __restrict__ hdr) {
  if (threadIdx.x == 0 && blockIdx.x == 0) {
    const int* off1 = hdr;
    const int* off2 = hdr + 9;
    int* toff = hdr + 18;
    int* ntcA = hdr + 28;
    int* ntrA = hdr + 36;
    int s = 0;
    for (int p = 0; p < T; ++p) {
      int c1 = off1[p + 1] - off1[p];
      int c2 = off2[p + 1] - off2[p];
      int ntr = (c1 + 127) / 128;
      int ntc = (c2 + 127) / 128;
      ntcA[p] = ntc;
      ntrA[p] = ntr;
      toff[p] = s;
      s += ntr * ntc;
    }
    toff[T] = s;
    hdr[27] = s;
  }
}

// ---------------------------------------------------------------------------
// cross_f16: out[i][j] = S1h[i][:].S2h[j][:] (K=128). Validated round 2.
// ---------------------------------------------------------------------------
__global__ __launch_bounds__(256) void cross_f16(
    const _Float16* __restrict__ S1h, const _Float16* __restrict__ S2h,
    float* __restrict__ out, int n2) {
  const int lane = threadIdx.x & 63;
  const int w = threadIdx.x >> 6;
  const int wr = w >> 1, wc = w & 1;
  const int bm = blockIdx.y * 128, bn = blockIdx.x * 128;
  const int lr = lane & 15;
  const int ko = (lane >> 4) * 8;

  f32x4 acc[4][4] = {};

  const _Float16* a_base = S1h + (size_t)(bm + wr * 64 + lr) * CLS + ko;
  const _Float16* b_base = S2h + (size_t)(bn + wc * 64 + lr) * CLS + ko;

#pragma unroll
  for (int kc = 0; kc < CLS / 32; ++kc) {
    half8 af[4], bf[4];
#pragma unroll
    for (int i = 0; i < 4; ++i) {
      af[i] = *reinterpret_cast<const half8*>(a_base + (size_t)i * 16 * CLS + kc * 32);
      bf[i] = *reinterpret_cast<const half8*>(b_base + (size_t)i * 16 * CLS + kc * 32);
    }
#pragma unroll
    for (int i = 0; i < 4; ++i)
#pragma unroll
      for (int j = 0; j < 4; ++j)
        acc[i][j] = __builtin_amdgcn_mfma_f32_16x16x32_f16(af[i], bf[j], acc[i][j], 0, 0, 0);
  }

  const int orow = bm + wr * 64 + (lane >> 4) * 4;
  const int ocol = bn + wc * 64 + (lane & 15);
#pragma unroll
  for (int i = 0; i < 4; ++i)
#pragma unroll
    for (int q = 0; q < 4; ++q) {
      float* dst = out + (size_t)(orow + i * 16 + q) * n2 + ocol;
#pragma unroll
      for (int j = 0; j < 4; ++j) dst[j * 16] = acc[i][j][q];
    }
}

// ---------------------------------------------------------------------------
// grouped_lds: dense per-type GEMM on sorted f16 operands, m97 2-phase
// structure: global_load_lds(16B) staging, double LDS buffer, one barrier
// per K-step. Type -> XCD affinity via p = blockIdx.x % T.
// ---------------------------------------------------------------------------
__global__ __launch_bounds__(256) void grouped_lds(
    const _Float16* __restrict__ G1, const _Float16* __restrict__ G2,
    const int* __restrict__ idx1, const int* __restrict__ idx2,
    const int* __restrict__ hdr, float* __restrict__ out,
    int K, int n2, int T, int stride) {
  __shared__ _Float16 As[2][128 * 32];
  __shared__ _Float16 Bs[2][128 * 32];
  const int* off1 = hdr;
  const int* off2 = hdr + 9;
  const int* ntcA = hdr + 28;
  const int* ntrA = hdr + 36;

  const int tid = threadIdx.x;
  const int lane = tid & 63, w = tid >> 6;
  const int wr = w >> 1, wc = w & 1;
  const int p = blockIdx.x % T;
  const int base1 = off1[p], base2 = off2[p];
  const int c1 = off1[p + 1] - base1, c2 = off2[p + 1] - base2;
  const int ntc = ntcA[p];
  const int ntiles = ntrA[p] * ntc;

  const int srow = tid >> 2;      // staging row within 64-row pass
  const int sk8 = (tid & 3) * 8;  // staging k offset (f16 elems)
  const size_t rowsK = (size_t)64 * K;

  for (int ti = blockIdx.x / T; ti < ntiles; ti += stride) {
    const int tr = ti / ntc, tc = ti % ntc;
    const int r0 = tr * 128, q0 = tc * 128;
    const _Float16* gA = G1 + (size_t)(base1 + r0 + srow) * K + sk8;
    const _Float16* gB = G2 + (size_t)(base2 + q0 + srow) * K + sk8;

    f32x4 acc[4][4] = {};
    int cur = 0;

    {  // prologue: stage k0 = 0 into buffer 0
      char* a0 = (char*)&As[0][0] + w * 1024;
      char* b0 = (char*)&Bs[0][0] + w * 1024;
      GLOAD(gA, a0); GLOAD(gA + rowsK, a0 + 4096);
      GLOAD(gB, b0); GLOAD(gB + rowsK, b0 + 4096);
    }
    __syncthreads();

    const int nk = K >> 5;
    for (int ks = 0; ks < nk; ++ks) {
      if (ks + 1 < nk) {  // issue next K-step's stage first (T3 minimum)
        const int k0 = (ks + 1) << 5;
        char* a0 = (char*)&As[cur ^ 1][0] + w * 1024;
        char* b0 = (char*)&Bs[cur ^ 1][0] + w * 1024;
        GLOAD(gA + k0, a0); GLOAD(gA + k0 + rowsK, a0 + 4096);
        GLOAD(gB + k0, b0); GLOAD(gB + k0 + rowsK, b0 + 4096);
      }
      const _Float16* A = &As[cur][0];
      const _Float16* B = &Bs[cur][0];
      half8 af[4], bf[4];
#pragma unroll
      for (int i = 0; i < 4; ++i) {
        af[i] = *reinterpret_cast<const half8*>(A + (wr * 64 + i * 16 + (lane & 15)) * 32 + (lane >> 4) * 8);
        bf[i] = *reinterpret_cast<const half8*>(B + (wc * 64 + i * 16 + (lane & 15)) * 32 + (lane >> 4) * 8);
      }
#pragma unroll
      for (int i = 0; i < 4; ++i)
#pragma unroll
        for (int j = 0; j < 4; ++j)
          acc[i][j] = __builtin_amdgcn_mfma_f32_16x16x32_f16(af[i], bf[j], acc[i][j], 0, 0, 0);
      __syncthreads();  // drains vmcnt(0): next buffer staged, this buffer free
      cur ^= 1;
    }

    // scatter epilogue: overwrite same-type pairs (validated round 2)
    int gcols[4];
#pragma unroll
    for (int j = 0; j < 4; ++j) {
      const int cl = wc * 64 + j * 16 + (lane & 15);
      gcols[j] = (q0 + cl < c2) ? idx2[base2 + q0 + cl] : -1;
    }
#pragma unroll
    for (int i = 0; i < 4; ++i) {
#pragma unroll
      for (int q = 0; q < 4; ++q) {
        const int rl = wr * 64 + i * 16 + (lane >> 4) * 4 + q;
        if (r0 + rl >= c1) continue;
        const int grow = idx1[base1 + r0 + rl];
        float* orow = out + (size_t)grow * n2;
#pragma unroll
        for (int j = 0; j < 4; ++j)
          if (gcols[j] >= 0) orow[gcols[j]] = acc[i][j][q];
      }
    }
  }
}

// ---------------------------------------------------------------------------
// Fallback grouped kernel (round-2, gathers from fp32 ft) if ws is small
// ---------------------------------------------------------------------------
__global__ __launch_bounds__(256) void grouped_f16_fb(
    const float* __restrict__ ft1, const float* __restrict__ ft2,
    const int* __restrict__ idx1, const int* __restrict__ idx2,
    const int* __restrict__ hdr, float* __restrict__ out,
    int d, int n2) {
  __shared__ _Float16 As[128 * 32];
  __shared__ _Float16 Bs[128 * 32];
  const int* off1 = hdr;
  const int* off2 = hdr + 9;
  const int* toff = hdr + 18;
  const int* ntcA = hdr + 28;
  const int total = hdr[27];

  const int tid = threadIdx.x;
  const int lane = tid & 63;
  const int w = tid >> 6;
  const int wr = w >> 1, wc = w & 1;
  const int srow = tid >> 1;
  const int shalf = tid & 1;
  const float4 zero4 = make_float4(0.f, 0.f, 0.f, 0.f);

  for (int wi = blockIdx.x; wi < total; wi += gridDim.x) {
    int p = 0;
    while (wi >= toff[p + 1]) ++p;
    const int local = wi - toff[p];
    const int ntc = ntcA[p];
    const int tr = local / ntc, tc = local % ntc;
    const int base1 = off1[p], base2 = off2[p];
    const int c1 = off1[p + 1] - base1, c2 = off2[p + 1] - base2;
    const int r0 = tr * 128, c0 = tc * 128;

    const bool va = (r0 + srow) < c1;
    const bool vb = (c0 + srow) < c2;
    const float* ap = ft1 + (size_t)(va ? idx1[base1 + r0 + srow] : 0) * d + shalf * 16;
    const float* bp = ft2 + (size_t)(vb ? idx2[base2 + c0 + srow] : 0) * d + shalf * 16;

    f32x4 acc[4][4] = {};
    float4 ra[4], rb[4];
#pragma unroll
    for (int q = 0; q < 4; ++q) {
      ra[q] = va ? *reinterpret_cast<const float4*>(ap + q * 4) : zero4;
      rb[q] = vb ? *reinterpret_cast<const float4*>(bp + q * 4) : zero4;
    }
    const int wbyte = srow * 64 + shalf * 32;
    const int wswz = (srow & 3) << 4;

    for (int k0 = 0; k0 < d; k0 += 32) {
      __syncthreads();
      {
        half8 ha0 = cvt8(ra[0], ra[1]), ha1 = cvt8(ra[2], ra[3]);
        half8 hb0 = cvt8(rb[0], rb[1]), hb1 = cvt8(rb[2], rb[3]);
        *reinterpret_cast<half8*>((char*)As + ((wbyte + 0) ^ wswz)) = ha0;
        *reinterpret_cast<half8*>((char*)As + ((wbyte + 16) ^ wswz)) = ha1;
        *reinterpret_cast<half8*>((char*)Bs + ((wbyte + 0) ^ wswz)) = hb0;
        *reinterpret_cast<half8*>((char*)Bs + ((wbyte + 16) ^ wswz)) = hb1;
      }
      __syncthreads();
      if (k0 + 32 < d) {
#pragma unroll
        for (int q = 0; q < 4; ++q) {
          ra[q] = va ? *reinterpret_cast<const float4*>(ap + k0 + 32 + q * 4) : zero4;
          rb[q] = vb ? *reinterpret_cast<const float4*>(bp + k0 + 32 + q * 4) : zero4;
        }
      }
      half8 af[4], bf[4];
#pragma unroll
      for (int i = 0; i < 4; ++i) {
        const int arow = wr * 64 + i * 16 + (lane & 15);
        const int aoff = (arow * 64 + (lane >> 4) * 16) ^ ((arow & 3) << 4);
        af[i] = *reinterpret_cast<const half8*>((const char*)As + aoff);
        const int brow = wc * 64 + i * 16 + (lane & 15);
        const int boff = (brow * 64 + (lane >> 4) * 16) ^ ((brow & 3) << 4);
        bf[i] = *reinterpret_cast<const half8*>((const char*)Bs + boff);
      }
#pragma unroll
      for (int i = 0; i < 4; ++i)
#pragma unroll
        for (int j = 0; j < 4; ++j)
          acc[i][j] = __builtin_amdgcn_mfma_f32_16x16x32_f16(af[i], bf[j], acc[i][j], 0, 0, 0);
    }

    int gcols[4];
#pragma unroll
    for (int j = 0; j < 4; ++j) {
      const int cl = wc * 64 + j * 16 + (lane & 15);
      gcols[j] = (c0 + cl < c2) ? idx2[base2 + c0 + cl] : -1;
    }
#pragma unroll
    for (int i = 0; i < 4; ++i) {
#pragma unroll
      for (int q = 0; q < 4; ++q) {
        const int rl = wr * 64 + i * 16 + (lane >> 4) * 4 + q;
        if (r0 + rl >= c1) continue;
        const int grow = idx1[base1 + r0 + rl];
        float* orow = out + (size_t)grow * n2;
#pragma unroll
        for (int j = 0; j < 4; ++j)
          if (gcols[j] >= 0) orow[gcols[j]] = acc[i][j][q];
      }
    }
    __syncthreads();
  }
}

// ---------------------------------------------------------------------------
extern "C" void kernel_launch(void* const* d_in, const int* in_sizes, int n_in,
                              void* d_out, int out_size, void* d_ws, size_t ws_size,
                              hipStream_t stream) {
  const float* ft1 = (const float*)d_in[0];
  const float* ft2 = (const float*)d_in[1];
  const int* t1 = (const int*)d_in[2];
  const int* t2 = (const int*)d_in[3];
  float* out = (float*)d_out;

  const int n1 = in_sizes[2];
  const int n2 = in_sizes[3];
  const int d = in_sizes[0] / n1;  // 1024
  const int T = d / CLS;           // 8

  const size_t grows1 = (size_t)n1 + 128, grows2 = (size_t)n2 + 128;
  const size_t need = (grows1 + grows2) * d * 2                  // G1h,G2h
                      + ((size_t)n1 + n2) * CLS * 2              // S1h,S2h
                      + ((size_t)n1 + n2) * 4 + 256;             // idx,hdr

  if (ws_size >= need) {
    _Float16* G1h = (_Float16*)d_ws;
    _Float16* G2h = G1h + grows1 * d;
    _Float16* S1h = G2h + grows2 * d;
    _Float16* S2h = S1h + (size_t)n1 * CLS;
    int* idx1 = (int*)(S2h + (size_t)n2 * CLS);
    int* idx2 = idx1 + n1;
    int* hdr = idx2 + n2;

    build_groups<<<2, 256, 0, stream>>>(t1, t2, n1, n2, T, idx1, idx2, hdr);
    build_tiles<<<1, 64, 0, stream>>>(T, hdr);
    gather_f16<<<(n1 * (CLS / 8) + 255) / 256, 256, 0, stream>>>(ft1, t1, S1h, n1, d);
    gather_f16<<<(n2 * (CLS / 8) + 255) / 256, 256, 0, stream>>>(ft2, t2, S2h, n2, d);
    gather_sorted<<<(int)((n1 * (size_t)(d / 8) + 255) / 256), 256, 0, stream>>>(ft1, idx1, G1h, n1, d);
    gather_sorted<<<(int)((n2 * (size_t)(d / 8) + 255) / 256), 256, 0, stream>>>(ft2, idx2, G2h, n2, d);

    dim3 grid(n2 / 128, n1 / 128);
    cross_f16<<<grid, 256, 0, stream>>>(S1h, S2h, out, n2);
    const int stride = 80;
    grouped_lds<<<T * stride, 256, 0, stream>>>(G1h, G2h, idx1, idx2, hdr, out, d, n2, T, stride);
  } else {
    _Float16* S1h = (_Float16*)d_ws;
    _Float16* S2h = S1h + (size_t)n1 * CLS;
    int* idx1 = (int*)(S2h + (size_t)n2 * CLS);
    int* idx2 = idx1 + n1;
    int* hdr = idx2 + n2;

    build_groups<<<2, 256, 0, stream>>>(t1, t2, n1, n2, T, idx1, idx2, hdr);
    build_tiles<<<1, 64, 0, stream>>>(T, hdr);
    gather_f16<<<(n1 * (CLS / 8) + 255) / 256, 256, 0, stream>>>(ft1, t1, S1h, n1, d);
    gather_f16<<<(n2 * (CLS / 8) + 255) / 256, 256, 0, stream>>>(ft2, t2, S2h, n2, d);

    dim3 grid(n2 / 128, n1 / 128);
    cross_f16<<<grid, 256, 0, stream>>>(S1h, S2h, out, n2);
    grouped_f16_fb<<<1024, 256, 0, stream>>>(ft1, ft2, idx1, idx2, hdr, out, d, n2);
  }
}